// Round 1
// baseline (3868.023 us; speedup 1.0000x reference)
//
#include <hip/hip_runtime.h>
#include <math.h>

#define Bn 256
#define Tn 300
#define Nn 512
#define NB 64
#define LDV 68   // pad for float4 LDS rows: 68*4=272B, 16B aligned; row spans 2-way bank alias = free
#define LDA 65   // pad for column-wise access in diag Cholesky

// shared-array accessors (each kernel declares sVd/sTa/sTbAd locally)
#define AD(r,c) sTbAd[(r)*LDA+(c)]
#define VD(r,c) sVd[(r)*LDV+(c)]
#define TA(r,c) sTa[(r)*LDV+(c)]
#define TB(r,c) sTbAd[(r)*LDV+(c)]

// K1: gamma[b,d] = sum_t x[b,t,d]*w[b,t]; Nsum[b] = sum_t w[b,t]
__global__ __launch_bounds__(256) void k_gamma(const float* __restrict__ x,
                                               const float* __restrict__ w,
                                               float* __restrict__ gamma,
                                               float* __restrict__ Nsum) {
  int b = blockIdx.x, tid = threadIdx.x;
  const float* xb = x + (size_t)b * Tn * Nn;
  const float* wb = w + b * Tn;
  float g0 = 0.f, g1 = 0.f, ns = 0.f;
  for (int t = 0; t < Tn; t++) {
    float wt = wb[t];
    ns += wt;
    g0 += xb[(size_t)t * Nn + tid] * wt;
    g1 += xb[(size_t)t * Nn + tid + 256] * wt;
  }
  gamma[b * Nn + tid] = g0;
  gamma[b * Nn + tid + 256] = g1;
  if (tid == 0) Nsum[b] = ns;
}

// K2: C = diag(exp(0.5*Dw)) * chol_w, stored FULL with explicit zeros below diagonal
__global__ __launch_bounds__(256) void k_prepC(const float* __restrict__ Dw,
                                               const float* __restrict__ cholw,
                                               float* __restrict__ C) {
  int r = blockIdx.x, tid = threadIdx.x;
  float s = expf(0.5f * Dw[r]);
  for (int c = tid; c < Nn; c += 256)
    C[r * Nn + c] = (c >= r) ? s * cholw[r * Nn + c] : 0.f;
}

// K3: CCT = C*C^T (upper 32x32 tiles only; that's all k_factor reads)
__global__ __launch_bounds__(256) void k_cct(const float* __restrict__ C,
                                             float* __restrict__ CCT) {
  __shared__ float Ci[32][33];
  __shared__ float Cj[32][33];
  int tid = threadIdx.x;
  int idx = blockIdx.x, ti = 0;
  while (idx >= 16 - ti) { idx -= 16 - ti; ti++; }
  int tj = ti + idx;
  int i0 = ti * 32, j0 = tj * 32;
  float acc[4] = {0.f, 0.f, 0.f, 0.f};
  int r = tid >> 3, c0 = tid & 7;
  for (int kt = j0; kt < Nn; kt += 32) {  // C rows j0.. are zero for k<j0
    __syncthreads();
    for (int q = tid; q < 1024; q += 256) {
      int rr = q >> 5, cc = q & 31;
      Ci[rr][cc] = C[(size_t)(i0 + rr) * Nn + kt + cc];
      Cj[rr][cc] = C[(size_t)(j0 + rr) * Nn + kt + cc];
    }
    __syncthreads();
    for (int k = 0; k < 32; k++) {
      float a = Ci[r][k];
#pragma unroll
      for (int j = 0; j < 4; j++) acc[j] += a * Cj[c0 + 8 * j][k];
    }
  }
#pragma unroll
  for (int j = 0; j < 4; j++)
    CCT[(size_t)(i0 + r) * Nn + j0 + c0 + 8 * j] = acc[j];
}

// K4: per batch b: S = CCT + Nb*I (upper); reverse-Cholesky S = U*U^T (U upper),
// written in place into the chol output region (scratch). Blocked, NB=64 panels.
__global__ __launch_bounds__(256) void k_factor(const float* __restrict__ CCT,
                                                const float* __restrict__ Nsum,
                                                float* __restrict__ cholG) {
  int b = blockIdx.x, tid = threadIdx.x;
  float* A = cholG + (size_t)b * Nn * Nn;
  float Nb = Nsum[b];
  __shared__ __align__(16) float sVd[NB * LDV];
  __shared__ __align__(16) float sTa[NB * LDV];
  __shared__ __align__(16) float sTbAd[NB * LDV];  // Tb aliases Ad (disjoint lifetimes)
  // init upper triangle
  for (int q = tid; q < Nn * Nn; q += 256) {
    int r = q >> 9, c = q & 511;
    if (c >= r) A[q] = CCT[q] + (c == r ? Nb : 0.f);
  }
  const int tr = tid >> 4, tc = tid & 15;
  for (int p = 7; p >= 0; p--) {
    const int j0 = p * NB;
    __syncthreads();
    // load diag block (upper, zeros below); zero Vd
    for (int q = tid; q < NB * NB; q += 256) {
      int r = q >> 6, c = q & 63;
      AD(r, c) = (c >= r) ? A[(size_t)(j0 + r) * Nn + j0 + c] : 0.f;
      VD(r, c) = 0.f;
    }
    __syncthreads();
    // reverse Cholesky of 64x64 diag block: A = U U^T, columns high->low
    for (int c = NB - 1; c >= 0; c--) {
      float dcc = AD(c, c);
      float rs = rsqrtf(dcc);
      if (tid < c) AD(tid, c) *= rs;
      else if (tid == c) AD(c, c) = dcc * rs;
      __syncthreads();
      int j = tid & 63, i0 = tid >> 6;
      if (j < c) {
        float ujc = AD(j, c);
        for (int i = i0; i <= j; i += 4) AD(i, j) -= AD(i, c) * ujc;
      }
      __syncthreads();
    }
    // invert Ujj -> Vd (row back-substitution, bottom-up)
    for (int r = NB - 1; r >= 0; r--) {
      if (tid < NB) {
        int c = tid;
        float s = (c == r) ? 1.f : 0.f;
        for (int k = r + 1; k < NB; k++) s -= AD(r, k) * VD(k, c);
        VD(r, c) = s / AD(r, r);
      }
      __syncthreads();
    }
    // write Ujj back
    for (int q = tid; q < NB * NB; q += 256) {
      int r = q >> 6, c = q & 63;
      if (c >= r) A[(size_t)(j0 + r) * Nn + j0 + c] = AD(r, c);
    }
    // trsm: X = A[rt:rt+64, J] * Vd^T  (X * Ujj^T = A_panel)
    for (int rt = 0; rt < j0; rt += NB) {
      __syncthreads();
      for (int q = tid; q < NB * NB; q += 256) {
        int r = q >> 6, c = q & 63;
        TA(r, c) = A[(size_t)(rt + r) * Nn + j0 + c];
      }
      __syncthreads();
      float acc[4][4] = {};
      for (int k = 0; k < NB; k += 4) {
        float4 av[4], bv[4];
#pragma unroll
        for (int i = 0; i < 4; i++) av[i] = *(const float4*)&TA(tr * 4 + i, k);
#pragma unroll
        for (int j = 0; j < 4; j++) bv[j] = *(const float4*)&VD(tc + 16 * j, k);
#pragma unroll
        for (int i = 0; i < 4; i++)
#pragma unroll
          for (int j = 0; j < 4; j++)
            acc[i][j] += av[i].x * bv[j].x + av[i].y * bv[j].y +
                         av[i].z * bv[j].z + av[i].w * bv[j].w;
      }
      __syncthreads();
#pragma unroll
      for (int i = 0; i < 4; i++)
#pragma unroll
        for (int j = 0; j < 4; j++)
          A[(size_t)(rt + tr * 4 + i) * Nn + j0 + tc + 16 * j] = acc[i][j];
    }
    // syrk: A[0:j0,0:j0] -= X * X^T  (upper tiles; diag-tile lower is never-read scratch)
    for (int it = 0; it < p; it++) {
      __syncthreads();
      for (int q = tid; q < NB * NB; q += 256) {
        int r = q >> 6, c = q & 63;
        TA(r, c) = A[(size_t)(it * NB + r) * Nn + j0 + c];
      }
      for (int jt = it; jt < p; jt++) {
        __syncthreads();
        for (int q = tid; q < NB * NB; q += 256) {
          int r = q >> 6, c = q & 63;
          TB(r, c) = A[(size_t)(jt * NB + r) * Nn + j0 + c];
        }
        __syncthreads();
        float acc[4][4] = {};
        for (int k = 0; k < NB; k += 4) {
          float4 av[4], bv[4];
#pragma unroll
          for (int i = 0; i < 4; i++) av[i] = *(const float4*)&TA(tr * 4 + i, k);
#pragma unroll
          for (int j = 0; j < 4; j++) bv[j] = *(const float4*)&TB(tc + 16 * j, k);
#pragma unroll
          for (int i = 0; i < 4; i++)
#pragma unroll
            for (int j = 0; j < 4; j++)
              acc[i][j] += av[i].x * bv[j].x + av[i].y * bv[j].y +
                           av[i].z * bv[j].z + av[i].w * bv[j].w;
        }
#pragma unroll
        for (int i = 0; i < 4; i++)
#pragma unroll
          for (int j = 0; j < 4; j++) {
            size_t o = (size_t)(it * NB + tr * 4 + i) * Nn + jt * NB + tc + 16 * j;
            A[o] -= acc[i][j];
          }
      }
    }
  }
}

// K5: per batch: solve U * G = C for G (upper), in place over U.
// Row-blocks R descending; within R, column-blocks J descending (in-place safe).
__global__ __launch_bounds__(256) void k_solve(const float* __restrict__ C,
                                               float* __restrict__ cholG) {
  int b = blockIdx.x, tid = threadIdx.x;
  float* A = cholG + (size_t)b * Nn * Nn;
  __shared__ __align__(16) float sVd[NB * LDV];
  __shared__ __align__(16) float sTa[NB * LDV];
  __shared__ __align__(16) float sTbAd[NB * LDV];
  const int tr = tid >> 4, tc = tid & 15;
  for (int R = 7; R >= 0; R--) {
    __syncthreads();
    for (int q = tid; q < NB * NB; q += 256) {
      int r = q >> 6, c = q & 63;
      AD(r, c) = (c >= r) ? A[(size_t)(R * NB + r) * Nn + R * NB + c] : 0.f;
      VD(r, c) = 0.f;
    }
    __syncthreads();
    // Vd = Urr^{-1}
    for (int r = NB - 1; r >= 0; r--) {
      if (tid < NB) {
        int c = tid;
        float s = (c == r) ? 1.f : 0.f;
        for (int k = r + 1; k < NB; k++) s -= AD(r, k) * VD(k, c);
        VD(r, c) = s / AD(r, r);
      }
      __syncthreads();
    }
    for (int J = 7; J >= R; J--) {
      float acc[4][4];
#pragma unroll
      for (int i = 0; i < 4; i++)
#pragma unroll
        for (int j = 0; j < 4; j++)
          acc[i][j] = C[(size_t)(R * NB + tr * 4 + i) * Nn + J * NB + tc + 16 * j];
      for (int K = R + 1; K <= J; K++) {
        __syncthreads();
        for (int q = tid; q < NB * NB; q += 256) {
          int r = q >> 6, c = q & 63;
          TA(r, c) = A[(size_t)(R * NB + r) * Nn + K * NB + c];  // U[R,K]
          TB(r, c) = A[(size_t)(K * NB + r) * Nn + J * NB + c];  // G[K,J]
        }
        __syncthreads();
        for (int k = 0; k < NB; k += 4) {
          float a4[4][4];
#pragma unroll
          for (int i = 0; i < 4; i++) {
            float4 t = *(const float4*)&TA(tr * 4 + i, k);
            a4[i][0] = t.x; a4[i][1] = t.y; a4[i][2] = t.z; a4[i][3] = t.w;
          }
#pragma unroll
          for (int kk = 0; kk < 4; kk++) {
            float bb[4];
#pragma unroll
            for (int j = 0; j < 4; j++) bb[j] = TB(k + kk, tc + 16 * j);
#pragma unroll
            for (int i = 0; i < 4; i++)
#pragma unroll
              for (int j = 0; j < 4; j++) acc[i][j] -= a4[i][kk] * bb[j];
          }
        }
      }
      __syncthreads();
#pragma unroll
      for (int i = 0; i < 4; i++)
#pragma unroll
        for (int j = 0; j < 4; j++) TA(tr * 4 + i, tc + 16 * j) = acc[i][j];
      __syncthreads();
      // G[R,J] = Vd * temp
      float out[4][4] = {};
      for (int k = 0; k < NB; k += 4) {
        float v4[4][4];
#pragma unroll
        for (int i = 0; i < 4; i++) {
          float4 t = *(const float4*)&VD(tr * 4 + i, k);
          v4[i][0] = t.x; v4[i][1] = t.y; v4[i][2] = t.z; v4[i][3] = t.w;
        }
#pragma unroll
        for (int kk = 0; kk < 4; kk++) {
          float bb[4];
#pragma unroll
          for (int j = 0; j < 4; j++) bb[j] = TA(k + kk, tc + 16 * j);
#pragma unroll
          for (int i = 0; i < 4; i++)
#pragma unroll
            for (int j = 0; j < 4; j++) out[i][j] += v4[i][kk] * bb[j];
        }
      }
#pragma unroll
      for (int i = 0; i < 4; i++)
#pragma unroll
        for (int j = 0; j < 4; j++)
          A[(size_t)(R * NB + tr * 4 + i) * Nn + J * NB + tc + 16 * j] = out[i][j];
    }
  }
}

// K6: y = G*gamma, mu = G^T y, logvar = 2 log diag(G), chol = G / diag (rows),
// zero strict lower triangle. One row per wave per iteration; barrier-free reduce.
__global__ __launch_bounds__(256) void k_finish(const float* __restrict__ gam,
                                                float* __restrict__ mu,
                                                float* __restrict__ logvar,
                                                float* __restrict__ cholG) {
  int b = blockIdx.x, tid = threadIdx.x;
  float* A = cholG + (size_t)b * Nn * Nn;
  __shared__ float gsh[Nn];
  __shared__ float mup[4][Nn];
  for (int c = tid; c < Nn; c += 256) gsh[c] = gam[b * Nn + c];
  for (int c = tid; c < 4 * Nn; c += 256) ((float*)mup)[c] = 0.f;
  __syncthreads();
  int w = tid >> 6, l = tid & 63;
  float mua[8] = {0.f, 0.f, 0.f, 0.f, 0.f, 0.f, 0.f, 0.f};
  for (int i = w; i < Nn; i += 4) {
    const size_t rowo = (size_t)i * Nn;
    float v[8];
    float s = 0.f;
#pragma unroll
    for (int j = 0; j < 8; j++) {
      int c = (j << 6) + l;
      v[j] = A[rowo + c];
      if (c >= i) s += v[j] * gsh[c];
    }
#pragma unroll
    for (int off = 32; off > 0; off >>= 1) s += __shfl_xor(s, off, 64);
    float d = A[rowo + i];  // wave-uniform diag load (before any store this iter)
    float rinv = 1.f / d;
    if (l == 0) logvar[b * Nn + i] = 2.f * logf(d);
#pragma unroll
    for (int j = 0; j < 8; j++) {
      int c = (j << 6) + l;
      if (c >= i) mua[j] += v[j] * s;
      float o = (c > i) ? v[j] * rinv : (c == i ? 1.f : 0.f);
      A[rowo + c] = o;
    }
  }
#pragma unroll
  for (int j = 0; j < 8; j++) mup[w][(j << 6) + l] = mua[j];
  __syncthreads();
  for (int c = tid; c < Nn; c += 256)
    mu[b * Nn + c] = mup[0][c] + mup[1][c] + mup[2][c] + mup[3][c];
}

extern "C" void kernel_launch(void* const* d_in, const int* in_sizes, int n_in,
                              void* d_out, int out_size, void* d_ws, size_t ws_size,
                              hipStream_t stream) {
  const float* x = (const float*)d_in[0];
  const float* w = (const float*)d_in[1];
  const float* Dw = (const float*)d_in[2];
  const float* cholw = (const float*)d_in[3];
  float* out = (float*)d_out;
  float* mu = out;                      // [B,512]
  float* logvar = out + Bn * Nn;        // [B,512]
  float* chol = out + 2 * Bn * Nn;      // [B,512,512] (used as scratch: S -> U -> G -> final)
  // scratch placement: gamma lives in mu region, Nsum in logvar region (both
  // consumed before those outputs are written); ws holds C and CCT (2 MB).
  float* gamma = mu;
  float* Nsum = logvar;
  float* Cm = (float*)d_ws;
  float* CCT = Cm + Nn * Nn;
  (void)in_sizes; (void)n_in; (void)out_size; (void)ws_size;

  k_gamma<<<Bn, 256, 0, stream>>>(x, w, gamma, Nsum);
  k_prepC<<<Nn, 256, 0, stream>>>(Dw, cholw, Cm);
  k_cct<<<136, 256, 0, stream>>>(Cm, CCT);
  k_factor<<<Bn, 256, 0, stream>>>(CCT, Nsum, chol);
  k_solve<<<Bn, 256, 0, stream>>>(Cm, chol);
  k_finish<<<Bn, 256, 0, stream>>>(gamma, mu, logvar, chol);
}

// Round 2
// 2498.254 us; speedup vs baseline: 1.5483x; 1.5483x over previous
//
#include <hip/hip_runtime.h>
#include <math.h>

#define Bn 256
#define Tn 300
#define Nn 512
#define NB 64
#define LDV 68   // stream/Vd pitch: breaks 16-row stride conflicts (measured 0 conflicts R1)
#define LDA 65   // diag-Cholesky pitch

#define TOFF(i,j) ((size_t)((i)*NB)*Nn + (size_t)(j)*NB)

// ---- helpers -------------------------------------------------------------
__device__ __forceinline__ void load_tile_f4(const float* __restrict__ g, int tid, float4 r[4]) {
#pragma unroll
  for (int t = 0; t < 4; t++) {
    int q = tid + 256 * t;          // f4 index 0..1023
    int row = q >> 4, c4 = q & 15;  // 64 rows x 16 float4
    r[t] = ((const float4*)(g + (size_t)row * Nn))[c4];
  }
}
__device__ __forceinline__ void store_stage(float* __restrict__ s, int tid, const float4 r[4]) {
#pragma unroll
  for (int t = 0; t < 4; t++) {
    int q = tid + 256 * t;
    int row = q >> 4, c4 = q & 15;
    *((float4*)(s + row * LDV + c4 * 4)) = r[t];
  }
}
// acc -= Arows · Brows^T (64-deep), 4x4 frag at (tr*4.., tc+16*..)
__device__ __forceinline__ void mm_nt_sub(const float* __restrict__ sa, const float* __restrict__ sb,
                                          int tr, int tc, float acc[4][4]) {
  for (int k = 0; k < NB; k += 4) {
    float4 av[4], bv[4];
#pragma unroll
    for (int i = 0; i < 4; i++) av[i] = *(const float4*)(sa + (tr * 4 + i) * LDV + k);
#pragma unroll
    for (int j = 0; j < 4; j++) bv[j] = *(const float4*)(sb + (tc + 16 * j) * LDV + k);
#pragma unroll
    for (int i = 0; i < 4; i++)
#pragma unroll
      for (int j = 0; j < 4; j++)
        acc[i][j] -= av[i].x * bv[j].x + av[i].y * bv[j].y + av[i].z * bv[j].z + av[i].w * bv[j].w;
  }
}

// K1: gamma[b,d] = sum_t x[b,t,d]*w[b,t]; Nsum[b] = sum_t w[b,t]
__global__ __launch_bounds__(256) void k_gamma(const float* __restrict__ x,
                                               const float* __restrict__ w,
                                               float* __restrict__ gamma,
                                               float* __restrict__ Nsum) {
  int b = blockIdx.x, tid = threadIdx.x;
  const float* xb = x + (size_t)b * Tn * Nn;
  const float* wb = w + b * Tn;
  float g0 = 0.f, g1 = 0.f, ns = 0.f;
  for (int t = 0; t < Tn; t++) {
    float wt = wb[t];
    ns += wt;
    g0 += xb[(size_t)t * Nn + tid] * wt;
    g1 += xb[(size_t)t * Nn + tid + 256] * wt;
  }
  gamma[b * Nn + tid] = g0;
  gamma[b * Nn + tid + 256] = g1;
  if (tid == 0) Nsum[b] = ns;
}

// K2: C = diag(exp(0.5*Dw)) * chol_w, full store with explicit zeros below diag
__global__ __launch_bounds__(256) void k_prepC(const float* __restrict__ Dw,
                                               const float* __restrict__ cholw,
                                               float* __restrict__ C) {
  int r = blockIdx.x, tid = threadIdx.x;
  float s = expf(0.5f * Dw[r]);
  for (int c = tid; c < Nn; c += 256)
    C[r * Nn + c] = (c >= r) ? s * cholw[r * Nn + c] : 0.f;
}

// K3: CCT = C*C^T. Upper 32x32 tiles (136) + the 8 below-diagonal tiles adjacent
// to the 64x64 diagonal blocks (needed by k_factor's full-tile reads).
__global__ __launch_bounds__(256) void k_cct(const float* __restrict__ C,
                                             float* __restrict__ CCT) {
  __shared__ float Ci[32][33];
  __shared__ float Cj[32][33];
  int tid = threadIdx.x;
  int idx = blockIdx.x, ti = 0, tj;
  if (idx < 136) {
    while (idx >= 16 - ti) { idx -= 16 - ti; ti++; }
    tj = ti + idx;
  } else {                 // lower sub-tile of 64x64 diag block j: (2j+1, 2j)
    ti = 2 * (idx - 136) + 1;
    tj = ti - 1;
  }
  int i0 = ti * 32, j0 = tj * 32;
  int m0 = (i0 > j0) ? i0 : j0;
  float acc[4] = {0.f, 0.f, 0.f, 0.f};
  int r = tid >> 3, c0 = tid & 7;
  for (int kt = m0; kt < Nn; kt += 32) {  // C rows are zero left of the diagonal
    __syncthreads();
    for (int q = tid; q < 1024; q += 256) {
      int rr = q >> 5, cc = q & 31;
      Ci[rr][cc] = C[(size_t)(i0 + rr) * Nn + kt + cc];
      Cj[rr][cc] = C[(size_t)(j0 + rr) * Nn + kt + cc];
    }
    __syncthreads();
    for (int k = 0; k < 32; k++) {
      float a = Ci[r][k];
#pragma unroll
      for (int j = 0; j < 4; j++) acc[j] += a * Cj[c0 + 8 * j][k];
    }
  }
#pragma unroll
  for (int j = 0; j < 4; j++)
    CCT[(size_t)(i0 + r) * Nn + j0 + c0 + 8 * j] = acc[j];
}

// K4 (left-looking, fused trsm): per batch b, reverse-Cholesky S = CCT + Nb*I = U U^T.
// Tile (i,j) accumulated once in registers over streamed k>j (double-buffered LDS),
// multiplied by Vd^T, written once. Vd (= Ujj^-1) stashed in dead lower tiles for k_solve.
__global__ __launch_bounds__(256) void k_factor(const float* __restrict__ CCT,
                                                const float* __restrict__ Nsum,
                                                float* __restrict__ AG) {
  const int b = blockIdx.x, tid = threadIdx.x;
  float* A = AG + (size_t)b * Nn * Nn;
  const float Nb = Nsum[b];
  __shared__ __align__(16) float sA[2][NB * LDV];
  __shared__ __align__(16) float sB[2][NB * LDV];
  __shared__ __align__(16) float sVd[NB * LDV];
  __shared__ float sAd[NB * LDA];
  const int tr = tid >> 4, tc = tid & 15;
  float4 ra[4], rb[4];

  for (int j = 7; j >= 0; j--) {
    const int nst = 7 - j;
    // ---------- diag tile: acc = CCT(j,j)+Nb*I - sum_k U(j,k)U(j,k)^T ----------
    float acc[4][4];
    {
      const float* T = CCT + TOFF(j, j);
#pragma unroll
      for (int i = 0; i < 4; i++) {
        const int r = tr * 4 + i;
#pragma unroll
        for (int jj = 0; jj < 4; jj++) {
          const int c = tc + 16 * jj;
          float v = T[(size_t)r * Nn + c];
          if (r == c) v += Nb;
          acc[i][jj] = v;
        }
      }
    }
    if (nst) load_tile_f4(A + TOFF(j, j + 1), tid, ra);
    __syncthreads();                       // previous phase done with sA/sB
    if (nst) store_stage(sA[0], tid, ra);
    __syncthreads();
    for (int kk = 0; kk < nst; kk++) {
      const int s = kk & 1;
      if (kk + 1 < nst) load_tile_f4(A + TOFF(j, j + 2 + kk), tid, ra);
      mm_nt_sub(sA[s], sA[s], tr, tc, acc);
      if (kk + 1 < nst) store_stage(sA[s ^ 1], tid, ra);
      __syncthreads();
    }
    // deposit to sAd (lower frags unused garbage-free: full tile is defined now)
#pragma unroll
    for (int i = 0; i < 4; i++)
#pragma unroll
      for (int jj = 0; jj < 4; jj++)
        sAd[(tr * 4 + i) * LDA + tc + 16 * jj] = acc[i][jj];
    __syncthreads();
    // reverse Cholesky of 64x64 (upper): columns high->low
    for (int c = NB - 1; c >= 0; c--) {
      float dcc = sAd[c * LDA + c];
      float rs = rsqrtf(dcc);
      if (tid < c) sAd[tid * LDA + c] *= rs;
      else if (tid == c) sAd[c * LDA + c] = dcc * rs;
      __syncthreads();
      int jj = tid & 63, i0 = tid >> 6;
      if (jj < c) {
        float ujc = sAd[jj * LDA + c];
        for (int i = i0; i <= jj; i += 4) sAd[i * LDA + jj] -= sAd[i * LDA + c] * ujc;
      }
      __syncthreads();
    }
    // Vd = Ujj^-1: zero, then barrier-free per-thread column back-substitution
    for (int q = tid; q < NB * LDV; q += 256) sVd[q] = 0.f;
    __syncthreads();
    if (tid < NB) {
      const int c = tid;  // column c: rows r=c..0, deps are thread-private
      for (int r = c; r >= 0; r--) {
        float s2 = (r == c) ? 1.f : 0.f;
        for (int k = r + 1; k <= c; k++) s2 -= sAd[r * LDA + k] * sVd[k * LDV + c];
        sVd[r * LDV + c] = s2 / sAd[r * LDA + r];
      }
    }
    __syncthreads();
    // stash Vd in a dead lower-triangle tile for k_solve
    {
      const int vr = (j < 7) ? 7 : 6, vc = (j < 7) ? j : 0;
      float* Vt = A + TOFF(vr, vc);
      for (int q = tid; q < NB * NB; q += 256) {
        int r = q >> 6, c = q & 63;
        Vt[(size_t)r * Nn + c] = sVd[r * LDV + c];
      }
    }
    // ---------- off-diag tiles: U(i,j) = (CCT(i,j) - sum_k U(i,k)U(j,k)^T) Vd^T ----------
    for (int i = j - 1; i >= 0; i--) {
      float acc2[4][4];
      {
        const float* T = CCT + TOFF(i, j);
#pragma unroll
        for (int ii = 0; ii < 4; ii++)
#pragma unroll
          for (int jj = 0; jj < 4; jj++)
            acc2[ii][jj] = T[(size_t)(tr * 4 + ii) * Nn + tc + 16 * jj];
      }
      if (nst) {
        load_tile_f4(A + TOFF(i, j + 1), tid, ra);
        load_tile_f4(A + TOFF(j, j + 1), tid, rb);
      }
      __syncthreads();                     // prev readers of sA/sB done
      if (nst) { store_stage(sA[0], tid, ra); store_stage(sB[0], tid, rb); }
      __syncthreads();
      for (int kk = 0; kk < nst; kk++) {
        const int s = kk & 1;
        if (kk + 1 < nst) {
          load_tile_f4(A + TOFF(i, j + 2 + kk), tid, ra);
          load_tile_f4(A + TOFF(j, j + 2 + kk), tid, rb);
        }
        mm_nt_sub(sA[s], sB[s], tr, tc, acc2);
        if (kk + 1 < nst) { store_stage(sA[s ^ 1], tid, ra); store_stage(sB[s ^ 1], tid, rb); }
        __syncthreads();
      }
      // trsm via round trip: X = acc2 · Vd^T
#pragma unroll
      for (int ii = 0; ii < 4; ii++)
#pragma unroll
        for (int jj = 0; jj < 4; jj++)
          sA[0][(tr * 4 + ii) * LDV + tc + 16 * jj] = acc2[ii][jj];
      __syncthreads();
      {
        float out[4][4] = {};
        for (int k = 0; k < NB; k += 4) {
          float4 av[4], bv[4];
#pragma unroll
          for (int ii = 0; ii < 4; ii++) av[ii] = *(const float4*)(sA[0] + (tr * 4 + ii) * LDV + k);
#pragma unroll
          for (int jj = 0; jj < 4; jj++) bv[jj] = *(const float4*)(sVd + (tc + 16 * jj) * LDV + k);
#pragma unroll
          for (int ii = 0; ii < 4; ii++)
#pragma unroll
            for (int jj = 0; jj < 4; jj++)
              out[ii][jj] += av[ii].x * bv[jj].x + av[ii].y * bv[jj].y +
                             av[ii].z * bv[jj].z + av[ii].w * bv[jj].w;
        }
        float* X = A + TOFF(i, j);
#pragma unroll
        for (int ii = 0; ii < 4; ii++)
#pragma unroll
          for (int jj = 0; jj < 4; jj++)
            X[(size_t)(tr * 4 + ii) * Nn + tc + 16 * jj] = out[ii][jj];
      }
      __syncthreads();                     // before next tile reuses sA[0]
    }
  }
}

// K5: per batch, solve U*G = C (G upper) in place over U; Vd read from stash.
__global__ __launch_bounds__(256) void k_solve(const float* __restrict__ C,
                                               float* __restrict__ AG) {
  const int b = blockIdx.x, tid = threadIdx.x;
  float* A = AG + (size_t)b * Nn * Nn;
  __shared__ __align__(16) float sA[2][NB * LDV];
  __shared__ __align__(16) float sB[2][NB * LDV];
  __shared__ __align__(16) float sVd[NB * LDV];
  const int tr = tid >> 4, tc = tid & 15;
  float4 ra[4], rb[4];
  for (int R = 7; R >= 0; R--) {
    {
      const int vr = (R < 7) ? 7 : 6, vc = (R < 7) ? R : 0;
      const float* Vt = A + TOFF(vr, vc);
      __syncthreads();                     // prev R's readers of sVd done
      for (int q = tid; q < NB * NB; q += 256) {
        int r = q >> 6, c = q & 63;
        sVd[r * LDV + c] = Vt[(size_t)r * Nn + c];
      }
      __syncthreads();
    }
    for (int J = 7; J >= R; J--) {
      const int nst = J - R;
      float acc[4][4];
      {
        const float* T = C + TOFF(R, J);
#pragma unroll
        for (int ii = 0; ii < 4; ii++)
#pragma unroll
          for (int jj = 0; jj < 4; jj++)
            acc[ii][jj] = T[(size_t)(tr * 4 + ii) * Nn + tc + 16 * jj];
      }
      if (nst) {
        load_tile_f4(A + TOFF(R, R + 1), tid, ra);
        load_tile_f4(A + TOFF(R + 1, J), tid, rb);
      }
      __syncthreads();
      if (nst) { store_stage(sA[0], tid, ra); store_stage(sB[0], tid, rb); }
      __syncthreads();
      for (int kk = 0; kk < nst; kk++) {
        const int s = kk & 1;
        if (kk + 1 < nst) {
          load_tile_f4(A + TOFF(R, R + 2 + kk), tid, ra);
          load_tile_f4(A + TOFF(R + 2 + kk, J), tid, rb);
        }
        // acc -= U(R,K) * G(K,J)   (A·B: b-side scalar reads, conflict-free)
        for (int k = 0; k < NB; k += 4) {
          float a4[4][4];
#pragma unroll
          for (int ii = 0; ii < 4; ii++) {
            float4 t = *(const float4*)(sA[s] + (tr * 4 + ii) * LDV + k);
            a4[ii][0] = t.x; a4[ii][1] = t.y; a4[ii][2] = t.z; a4[ii][3] = t.w;
          }
#pragma unroll
          for (int k2 = 0; k2 < 4; k2++) {
            float bb[4];
#pragma unroll
            for (int jj = 0; jj < 4; jj++) bb[jj] = sB[s][(k + k2) * LDV + tc + 16 * jj];
#pragma unroll
            for (int ii = 0; ii < 4; ii++)
#pragma unroll
              for (int jj = 0; jj < 4; jj++) acc[ii][jj] -= a4[ii][k2] * bb[jj];
          }
        }
        if (kk + 1 < nst) { store_stage(sA[s ^ 1], tid, ra); store_stage(sB[s ^ 1], tid, rb); }
        __syncthreads();
      }
      // round trip: temp -> sA[0]; G(R,J) = Vd * temp
#pragma unroll
      for (int ii = 0; ii < 4; ii++)
#pragma unroll
        for (int jj = 0; jj < 4; jj++)
          sA[0][(tr * 4 + ii) * LDV + tc + 16 * jj] = acc[ii][jj];
      __syncthreads();
      {
        float out[4][4] = {};
        for (int k = 0; k < NB; k += 4) {
          float v4[4][4];
#pragma unroll
          for (int ii = 0; ii < 4; ii++) {
            float4 t = *(const float4*)(sVd + (tr * 4 + ii) * LDV + k);
            v4[ii][0] = t.x; v4[ii][1] = t.y; v4[ii][2] = t.z; v4[ii][3] = t.w;
          }
#pragma unroll
          for (int k2 = 0; k2 < 4; k2++) {
            float bb[4];
#pragma unroll
            for (int jj = 0; jj < 4; jj++) bb[jj] = sA[0][(k + k2) * LDV + tc + 16 * jj];
#pragma unroll
            for (int ii = 0; ii < 4; ii++)
#pragma unroll
              for (int jj = 0; jj < 4; jj++) out[ii][jj] += v4[ii][k2] * bb[jj];
          }
        }
        float* G = A + TOFF(R, J);
#pragma unroll
        for (int ii = 0; ii < 4; ii++)
#pragma unroll
          for (int jj = 0; jj < 4; jj++)
            G[(size_t)(tr * 4 + ii) * Nn + tc + 16 * jj] = out[ii][jj];
      }
      __syncthreads();
    }
  }
}

// K6: y = G*gamma, mu = G^T y, logvar = 2 log diag(G), chol = G/diag rows,
// zero strict lower. One row per wave; barrier-free shuffle reduce.
__global__ __launch_bounds__(256) void k_finish(const float* __restrict__ gam,
                                                float* __restrict__ mu,
                                                float* __restrict__ logvar,
                                                float* __restrict__ cholG) {
  int b = blockIdx.x, tid = threadIdx.x;
  float* A = cholG + (size_t)b * Nn * Nn;
  __shared__ float gsh[Nn];
  __shared__ float mup[4][Nn];
  for (int c = tid; c < Nn; c += 256) gsh[c] = gam[b * Nn + c];
  for (int c = tid; c < 4 * Nn; c += 256) ((float*)mup)[c] = 0.f;
  __syncthreads();
  int w = tid >> 6, l = tid & 63;
  float mua[8] = {0.f, 0.f, 0.f, 0.f, 0.f, 0.f, 0.f, 0.f};
  for (int i = w; i < Nn; i += 4) {
    const size_t rowo = (size_t)i * Nn;
    float v[8];
    float s = 0.f;
#pragma unroll
    for (int j = 0; j < 8; j++) {
      int c = (j << 6) + l;
      v[j] = A[rowo + c];
      if (c >= i) s += v[j] * gsh[c];
    }
#pragma unroll
    for (int off = 32; off > 0; off >>= 1) s += __shfl_xor(s, off, 64);
    float d = A[rowo + i];
    float rinv = 1.f / d;
    if (l == 0) logvar[b * Nn + i] = 2.f * logf(d);
#pragma unroll
    for (int j = 0; j < 8; j++) {
      int c = (j << 6) + l;
      if (c >= i) mua[j] += v[j] * s;
      float o = (c > i) ? v[j] * rinv : (c == i ? 1.f : 0.f);
      A[rowo + c] = o;
    }
  }
#pragma unroll
  for (int j = 0; j < 8; j++) mup[w][(j << 6) + l] = mua[j];
  __syncthreads();
  for (int c = tid; c < Nn; c += 256)
    mu[b * Nn + c] = mup[0][c] + mup[1][c] + mup[2][c] + mup[3][c];
}

extern "C" void kernel_launch(void* const* d_in, const int* in_sizes, int n_in,
                              void* d_out, int out_size, void* d_ws, size_t ws_size,
                              hipStream_t stream) {
  const float* x = (const float*)d_in[0];
  const float* w = (const float*)d_in[1];
  const float* Dw = (const float*)d_in[2];
  const float* cholw = (const float*)d_in[3];
  float* out = (float*)d_out;
  float* mu = out;                  // [B,512]
  float* logvar = out + Bn * Nn;    // [B,512]
  float* chol = out + 2 * Bn * Nn;  // [B,512,512] scratch: U (+Vd stash) -> G -> final
  float* gamma = mu;                // consumed before mu written
  float* Nsum = logvar;             // consumed before logvar written
  float* Cm = (float*)d_ws;
  float* CCT = Cm + Nn * Nn;
  (void)in_sizes; (void)n_in; (void)out_size; (void)ws_size;

  k_gamma<<<Bn, 256, 0, stream>>>(x, w, gamma, Nsum);
  k_prepC<<<Nn, 256, 0, stream>>>(Dw, cholw, Cm);
  k_cct<<<144, 256, 0, stream>>>(Cm, CCT);
  k_factor<<<Bn, 256, 0, stream>>>(CCT, Nsum, chol);
  k_solve<<<Bn, 256, 0, stream>>>(Cm, chol);
  k_finish<<<Bn, 256, 0, stream>>>(gamma, mu, logvar, chol);
}